// Round 4
// baseline (651.980 us; speedup 1.0000x reference)
//
#include <hip/hip_runtime.h>

#define CDIM 384
#define NTOK 4096
#define NHEAD 12
#define KV_FLOATS (16 * NHEAD * 1024)
#define SCR_FLOATS (KV_FLOATS + 16 * CDIM)   // 202752 = 198*1024

typedef unsigned short ushort_t;
typedef __attribute__((ext_vector_type(8))) short bf16x8;
typedef __attribute__((ext_vector_type(4))) float f32x4;
typedef __attribute__((ext_vector_type(4))) unsigned short u16x4;
typedef __attribute__((ext_vector_type(8))) unsigned short u16x8;

__device__ __attribute__((aligned(16))) float g_scr[SCR_FLOATS];
__device__ int g_flag;

__device__ __forceinline__ float bf2f(ushort_t u) {
  union { unsigned int i; float f; } z; z.i = ((unsigned int)u) << 16; return z.f;
}
__device__ __forceinline__ ushort_t f2bf(float f) {
  union { float f; unsigned int i; } z; z.f = f;
  unsigned int r = z.i + 0x7FFFu + ((z.i >> 16) & 1u);
  return (ushort_t)(r >> 16);
}
__device__ __forceinline__ float ldf(const void* p, size_t i, bool fp32) {
  return fp32 ? ((const float*)p)[i] : bf2f(((const ushort_t*)p)[i]);
}

// load 8 elements at element-offset off from src, as bf16, 16B-store to dst
__device__ __forceinline__ void stage8(ushort_t* dst, const void* src, size_t off, bool fp32) {
  if (fp32) {
    const float* p = (const float*)src + off;
    f32x4 a = *(const f32x4*)p;
    f32x4 b = *(const f32x4*)(p + 4);
    u16x8 t;
    t[0] = f2bf(a[0]); t[1] = f2bf(a[1]); t[2] = f2bf(a[2]); t[3] = f2bf(a[3]);
    t[4] = f2bf(b[0]); t[5] = f2bf(b[1]); t[6] = f2bf(b[2]); t[7] = f2bf(b[3]);
    *(u16x8*)dst = t;
  } else {
    *(u16x8*)dst = *(const u16x8*)((const ushort_t*)src + off);
  }
}

// 128x128x384 bf16-MFMA GEMM tile (m97 structure), fp32 acc.
__device__ __forceinline__ void gemm128(const void* __restrict__ xsrc, size_t xoff,
                                        const void* __restrict__ wsrc, size_t woff,
                                        bool fp32, ushort_t* xs, ushort_t* wsm,
                                        int tid, f32x4 acc[4][4])
{
  f32x4 zz = {0.f, 0.f, 0.f, 0.f};
  #pragma unroll
  for (int i = 0; i < 4; ++i)
    #pragma unroll
    for (int j = 0; j < 4; ++j) acc[i][j] = zz;

  const int row1 = tid >> 2;
  const int kc   = (tid & 3) << 3;
  const size_t xo0 = xoff + (size_t)row1 * CDIM + kc;
  const size_t xo1 = xo0 + (size_t)64 * CDIM;
  const size_t wo0 = woff + (size_t)row1 * CDIM + kc;
  const size_t wo1 = wo0 + (size_t)64 * CDIM;
  ushort_t* d0 = xs + tid * 8;
  ushort_t* d1 = xs + 2048 + tid * 8;
  ushort_t* d2 = wsm + tid * 8;
  ushort_t* d3 = wsm + 2048 + tid * 8;

  const int lane = tid & 63, quad = lane >> 4, l15 = lane & 15;
  const int wv = tid >> 6, wm = wv >> 1, wn = wv & 1;
  const int arow = (wm * 64 + l15) * 32 + quad * 8;
  const int brow = (wn * 64 + l15) * 32 + quad * 8;

  for (int kk = 0; kk < CDIM; kk += 32) {
    stage8(d0, xsrc, xo0 + kk, fp32);
    stage8(d1, xsrc, xo1 + kk, fp32);
    stage8(d2, wsrc, wo0 + kk, fp32);
    stage8(d3, wsrc, wo1 + kk, fp32);
    __syncthreads();
    bf16x8 aF[4], bF[4];
    #pragma unroll
    for (int i = 0; i < 4; ++i) aF[i] = *(const bf16x8*)(xs + arow + i * 512);
    #pragma unroll
    for (int j = 0; j < 4; ++j) bF[j] = *(const bf16x8*)(wsm + brow + j * 512);
    #pragma unroll
    for (int i = 0; i < 4; ++i)
      #pragma unroll
      for (int j = 0; j < 4; ++j)
        acc[i][j] = __builtin_amdgcn_mfma_f32_16x16x32_bf16(aF[i], bF[j], acc[i][j], 0, 0, 0);
    __syncthreads();
  }
}

// prep: zero scratch + sniff input storage dtype (0 = bf16, 1 = fp32)
__global__ __launch_bounds__(256) void prep(const ushort_t* __restrict__ x) {
  int idx = (blockIdx.x * 256 + threadIdx.x) * 4;
  if (idx < SCR_FLOATS) {
    f32x4 z = {0.f, 0.f, 0.f, 0.f};
    *(f32x4*)(g_scr + idx) = z;
  }
  if (blockIdx.x == 0 && threadIdx.x < 64) {
    ushort_t u = x[threadIdx.x];
    int e = (u >> 7) & 0xFF;
    int ok = (e >= 117 && e <= 136) ? 1 : 0;
    unsigned long long m = __ballot(ok);
    if (threadIdx.x == 0) g_flag = (__popcll(m) >= 52) ? 0 : 1;
  }
}

// Kernel 1: k = elu(x@Wk^T + bk)+1 ; ksum += k (unroped) ; rope(k) ; kv += k_rope^T v
__global__ __launch_bounds__(256) void k1(const void* __restrict__ x,
                                          const void* __restrict__ qkw,
                                          const void* __restrict__ qkb)
{
  __shared__ __align__(16) char smem[33792];
  ushort_t* xs  = (ushort_t*)smem;
  ushort_t* wsm = xs + 4096;
  ushort_t* krope = (ushort_t*)smem;   // reused after GEMM: [128][132] bf16

  const bool fp32 = (g_flag != 0);
  const int tid = threadIdx.x;
  const int nt = blockIdx.x, ct = blockIdx.y, b = blockIdx.z;
  float* kv_g   = g_scr;
  float* ksum_g = g_scr + KV_FLOATS;

  f32x4 acc[4][4];
  gemm128(x,   ((size_t)b * NTOK + (size_t)nt * 128) * CDIM,
          qkw, (size_t)(CDIM + ct * 128) * CDIM, fp32, xs, wsm, tid, acc);

  const int lane = tid & 63, quad = lane >> 4, l15 = lane & 15;
  const int wv = tid >> 6, wm = wv >> 1, wn = wv & 1;

  // bias + elu + 1
  #pragma unroll
  for (int j = 0; j < 4; ++j) {
    const float bj = ldf(qkb, CDIM + ct * 128 + wn * 64 + j * 16 + l15, fp32);
    #pragma unroll
    for (int i = 0; i < 4; ++i)
      #pragma unroll
      for (int r = 0; r < 4; ++r) {
        float v = acc[i][j][r] + bj;
        acc[i][j][r] = v > 0.f ? v + 1.f : __expf(v);
      }
  }

  // unroped column sums -> ksum
  #pragma unroll
  for (int j = 0; j < 4; ++j) {
    float s = 0.f;
    #pragma unroll
    for (int i = 0; i < 4; ++i)
      #pragma unroll
      for (int r = 0; r < 4; ++r) s += acc[i][j][r];
    s += __shfl_down(s, 32);
    s += __shfl_down(s, 16);
    if (lane < 16)
      atomicAdd(&ksum_g[b * CDIM + ct * 128 + wn * 64 + j * 16 + l15], s);
  }

  // rope -> krope (bf16 in LDS, stride 132)
  float th[4]; bool sel[4];
  #pragma unroll
  for (int j = 0; j < 4; ++j) {
    int o = ct * 128 + wn * 64 + j * 16 + l15;
    int p = o >> 1;
    sel[j] = p < 96;
    int jj = sel[j] ? p : p - 96;
    th[j] = exp2f(-0.13841367062030676f * (float)jj);
  }
  #pragma unroll
  for (int i = 0; i < 4; ++i)
    #pragma unroll
    for (int r = 0; r < 4; ++r) {
      const int row  = wm * 64 + i * 16 + quad * 4 + r;
      const int ntok = nt * 128 + row;
      const float hhf = (float)(ntok >> 6), wwf = (float)(ntok & 63);
      #pragma unroll
      for (int j = 0; j < 4; ++j) {
        float ang = (sel[j] ? hhf : wwf) * th[j];
        float sn, cs;
        __sincosf(ang, &sn, &cs);
        float v0 = acc[i][j][r];
        float other = __shfl_xor(v0, 1);
        if (!(lane & 1)) {
          ushort2 t = make_ushort2(f2bf(cs * v0 - sn * other), f2bf(sn * v0 + cs * other));
          *(ushort2*)(krope + row * 132 + wn * 64 + j * 16 + l15) = t;
        }
      }
    }
  __syncthreads();

  // kv[b][h][dd][e] += sum_n k_rope[n][dd] * v[n][e]
  const int hl  = tid >> 6;
  const int ddg = lane >> 3;
  const int eg  = lane & 7;
  const size_t vbase = ((size_t)b * NTOK + (size_t)nt * 128) * CDIM + ct * 128 + hl * 32 + eg * 4;
  const ushort_t* krh = krope + hl * 32 + ddg * 4;
  float kvp[4][4];
  #pragma unroll
  for (int di = 0; di < 4; ++di)
    #pragma unroll
    for (int ei = 0; ei < 4; ++ei) kvp[di][ei] = 0.f;

  #pragma unroll 4
  for (int n = 0; n < 128; ++n) {
    u16x4 kr = *(const u16x4*)(krh + n * 132);
    float kf0 = bf2f(kr[0]), kf1 = bf2f(kr[1]), kf2 = bf2f(kr[2]), kf3 = bf2f(kr[3]);
    float ve0, ve1, ve2, ve3;
    if (fp32) {
      f32x4 vv = *(const f32x4*)((const float*)x + vbase + (size_t)n * CDIM);
      ve0 = vv[0]; ve1 = vv[1]; ve2 = vv[2]; ve3 = vv[3];
    } else {
      u16x4 vv = *(const u16x4*)((const ushort_t*)x + vbase + (size_t)n * CDIM);
      ve0 = bf2f(vv[0]); ve1 = bf2f(vv[1]); ve2 = bf2f(vv[2]); ve3 = bf2f(vv[3]);
    }
    kvp[0][0] += kf0*ve0; kvp[0][1] += kf0*ve1; kvp[0][2] += kf0*ve2; kvp[0][3] += kf0*ve3;
    kvp[1][0] += kf1*ve0; kvp[1][1] += kf1*ve1; kvp[1][2] += kf1*ve2; kvp[1][3] += kf1*ve3;
    kvp[2][0] += kf2*ve0; kvp[2][1] += kf2*ve1; kvp[2][2] += kf2*ve2; kvp[2][3] += kf2*ve3;
    kvp[3][0] += kf3*ve0; kvp[3][1] += kf3*ve1; kvp[3][2] += kf3*ve2; kvp[3][3] += kf3*ve3;
  }
  float* kvdst = kv_g + (size_t)(b * NHEAD + ct * 4 + hl) * 1024 + (ddg * 4) * 32 + eg * 4;
  #pragma unroll
  for (int di = 0; di < 4; ++di)
    #pragma unroll
    for (int ei = 0; ei < 4; ++ei)
      atomicAdd(kvdst + di * 32 + ei, kvp[di][ei]);
}

// Kernel 2: q = elu(x@Wq^T + bq)+1 ; z = 1/(q . kmean + eps) ; rope(q) ;
//           out = z * (q_rope @ kv/n) + LePE(v)   [output dtype = input dtype]
__global__ __launch_bounds__(256) void k2(const void* __restrict__ x,
                                          const void* __restrict__ qkw,
                                          const void* __restrict__ qkb,
                                          const void* __restrict__ lepw,
                                          const void* __restrict__ lepb,
                                          void* __restrict__ out)
{
  __shared__ __align__(16) char smem[50176];
  ushort_t* xs  = (ushort_t*)smem;
  ushort_t* wsm = xs + 4096;
  ushort_t* qr  = (ushort_t*)smem;             // reused after GEMM: [128][136] bf16
  ushort_t* kvT = (ushort_t*)(smem + 34816);   // [4][e=32][dd=32] bf16
  float* zl = (float*)(smem + 43008);          // [128][4]
  float* lw = (float*)(smem + 45056);          // [128][9]
  float* lb = (float*)(smem + 49664);          // [128]

  const bool fp32 = (g_flag != 0);
  const int tid = threadIdx.x;
  const int nt = blockIdx.x, ct = blockIdx.y, b = blockIdx.z;
  const float* kv_g   = g_scr;
  const float* ksum_g = g_scr + KV_FLOATS;

  for (int g = tid; g < 1152; g += 256) lw[g] = ldf(lepw, (size_t)ct * 1152 + g, fp32);
  if (tid < 128) lb[tid] = ldf(lepb, ct * 128 + tid, fp32);

  f32x4 acc[4][4];
  gemm128(x,   ((size_t)b * NTOK + (size_t)nt * 128) * CDIM,
          qkw, (size_t)(ct * 128) * CDIM, fp32, xs, wsm, tid, acc);

  const int lane = tid & 63, quad = lane >> 4, l15 = lane & 15;
  const int wv = tid >> 6, wm = wv >> 1, wn = wv & 1;

  // bias + elu + 1
  #pragma unroll
  for (int j = 0; j < 4; ++j) {
    const float bj = ldf(qkb, ct * 128 + wn * 64 + j * 16 + l15, fp32);
    #pragma unroll
    for (int i = 0; i < 4; ++i)
      #pragma unroll
      for (int r = 0; r < 4; ++r) {
        float v = acc[i][j][r] + bj;
        acc[i][j][r] = v > 0.f ? v + 1.f : __expf(v);
      }
  }

  // z = 1/(q . kmean + 1e-6)
  float km[4];
  #pragma unroll
  for (int j = 0; j < 4; ++j)
    km[j] = ksum_g[b * CDIM + ct * 128 + wn * 64 + j * 16 + l15] * (1.f / 4096.f);
  #pragma unroll
  for (int i = 0; i < 4; ++i)
    #pragma unroll
    for (int r = 0; r < 4; ++r) {
      float p0 = acc[i][0][r] * km[0] + acc[i][1][r] * km[1];
      float p1 = acc[i][2][r] * km[2] + acc[i][3][r] * km[3];
      #pragma unroll
      for (int off = 8; off > 0; off >>= 1) {
        p0 += __shfl_down(p0, off, 16);
        p1 += __shfl_down(p1, off, 16);
      }
      if (l15 == 0) {
        int row = wm * 64 + i * 16 + quad * 4 + r;
        zl[row * 4 + wn * 2]     = 1.f / (p0 + 1e-6f);
        zl[row * 4 + wn * 2 + 1] = 1.f / (p1 + 1e-6f);
      }
    }

  // rope -> qr (bf16, stride 136)
  float th[4]; bool sel[4];
  #pragma unroll
  for (int j = 0; j < 4; ++j) {
    int o = ct * 128 + wn * 64 + j * 16 + l15;
    int p = o >> 1;
    sel[j] = p < 96;
    int jj = sel[j] ? p : p - 96;
    th[j] = exp2f(-0.13841367062030676f * (float)jj);
  }
  #pragma unroll
  for (int i = 0; i < 4; ++i)
    #pragma unroll
    for (int r = 0; r < 4; ++r) {
      const int row  = wm * 64 + i * 16 + quad * 4 + r;
      const int ntok = nt * 128 + row;
      const float hhf = (float)(ntok >> 6), wwf = (float)(ntok & 63);
      #pragma unroll
      for (int j = 0; j < 4; ++j) {
        float ang = (sel[j] ? hhf : wwf) * th[j];
        float sn, cs;
        __sincosf(ang, &sn, &cs);
        float v0 = acc[i][j][r];
        float other = __shfl_xor(v0, 1);
        if (!(lane & 1)) {
          ushort2 t = make_ushort2(f2bf(cs * v0 - sn * other), f2bf(sn * v0 + cs * other));
          *(ushort2*)(qr + row * 136 + wn * 64 + j * 16 + l15) = t;
        }
      }
    }

  // stage kv (scaled 1/n) into LDS as bf16 [h][e][dd]
  const float* kvb = kv_g + (size_t)(b * NHEAD + ct * 4) * 1024;
  #pragma unroll
  for (int s = 0; s < 16; ++s) {
    int g = s * 256 + tid;
    int hl2 = g >> 10, dd = (g >> 5) & 31, e = g & 31;
    kvT[hl2 * 1024 + e * 32 + dd] = f2bf(kvb[g] * (1.f / 4096.f));
  }
  __syncthreads();

  // out-projection via MFMA: D[row][e] = q_rope[row][dd] * kv[dd][e], one wave per head
  const int hl = tid >> 6;
  bf16x8 aF[8];
  #pragma unroll
  for (int i = 0; i < 8; ++i)
    aF[i] = *(const bf16x8*)(qr + (i * 16 + l15) * 136 + hl * 32 + quad * 8);
  f32x4 oac[8][2];
  f32x4 zz = {0.f, 0.f, 0.f, 0.f};
  #pragma unroll
  for (int i = 0; i < 8; ++i) { oac[i][0] = zz; oac[i][1] = zz; }
  #pragma unroll
  for (int jn = 0; jn < 2; ++jn) {
    bf16x8 bF = *(const bf16x8*)(kvT + hl * 1024 + (jn * 16 + l15) * 32 + quad * 8);
    #pragma unroll
    for (int i = 0; i < 8; ++i)
      oac[i][jn] = __builtin_amdgcn_mfma_f32_16x16x32_bf16(aF[i], bF, oac[i][jn], 0, 0, 0);
  }

  // epilogue: * z, + LePE, store (fp32 or bf16, matching input storage dtype)
  #pragma unroll
  for (int i = 0; i < 8; ++i)
    #pragma unroll
    for (int jn = 0; jn < 2; ++jn)
      #pragma unroll
      for (int r = 0; r < 4; ++r) {
        const int row  = i * 16 + quad * 4 + r;
        const int e    = jn * 16 + l15;
        const int chl  = hl * 32 + e;
        const int ch   = ct * 128 + chl;
        const int ntok = nt * 128 + row;
        const int hh = ntok >> 6, ww = ntok & 63;
        float val = oac[i][jn][r] * zl[row * 4 + hl];
        float lep = lb[chl];
        #pragma unroll
        for (int ky = 0; ky < 3; ++ky) {
          int ih = hh + ky - 1;
          if ((unsigned)ih < 64u) {
            #pragma unroll
            for (int kx = 0; kx < 3; ++kx) {
              int iw = ww + kx - 1;
              if ((unsigned)iw < 64u) {
                size_t vidx = ((size_t)b * NTOK + (size_t)(ih * 64 + iw)) * CDIM + ch;
                lep += lw[chl * 9 + ky * 3 + kx] * ldf(x, vidx, fp32);
              }
            }
          }
        }
        size_t oi = ((size_t)b * NTOK + ntok) * CDIM + ch;
        float res = val + lep;
        if (fp32) ((float*)out)[oi] = res;
        else      ((ushort_t*)out)[oi] = f2bf(res);
      }
}

extern "C" void kernel_launch(void* const* d_in, const int* in_sizes, int n_in,
                              void* d_out, int out_size, void* d_ws, size_t ws_size,
                              hipStream_t stream) {
  const void* x    = d_in[0];
  const void* qkw  = d_in[1];
  const void* qkb  = d_in[2];
  const void* lepw = d_in[3];
  const void* lepb = d_in[4];

  prep<<<198, 256, 0, stream>>>((const ushort_t*)x);
  dim3 grid(32, 3, 16), blk(256, 1, 1);
  k1<<<grid, blk, 0, stream>>>(x, qkw, qkb);
  k2<<<grid, blk, 0, stream>>>(x, qkw, qkb, lepw, lepb, d_out);
}